// Round 5
// baseline (167.950 us; speedup 1.0000x reference)
//
#include <hip/hip_runtime.h>
#include <hip/hip_cooperative_groups.h>

namespace cg = cooperative_groups;

// Problem constants (from reference): B=8, N=65536, P=12, G=64
#define BB 8
#define NN 65536
#define PP 12
#define GG 64
#define G3 (GG*GG*GG)
#define NBLOCKS 2048   // (B*N)/256 ; == 8 blocks/CU * 256 CUs (exact co-residency)

// Contribution of reflecting point (px,py,pz) across raw plane pl.
// Matches reference math: normalize plane in f32, reflect, idx3 = ceil((r+0.5)*G-0.5),
// combine in int32 (wraps identically), clip combined index, mask = 1 - voxel.
__device__ __forceinline__ float plane_contrib(
    float px, float py, float pz, float4 pl,
    const float* __restrict__ cpb, const float* __restrict__ voxb)
{
    float nx = pl.x, ny = pl.y, nz = pl.z, d = pl.w;
    float norm = sqrtf(nx * nx + ny * ny + nz * nz);
    float inv = 1.0f / norm;
    nx *= inv; ny *= inv; nz *= inv; d *= inv;

    float t = 2.0f * (px * nx + py * ny + pz * nz + d);
    float rx = px - t * nx;
    float ry = py - t * ny;
    float rz = pz - t * nz;

    int ix = (int)ceilf((rx + 0.5f) * 64.0f - 0.5f);
    int iy = (int)ceilf((ry + 0.5f) * 64.0f - 0.5f);
    int iz = (int)ceilf((rz + 0.5f) * 64.0f - 0.5f);
    int idx = ix * 4096 + iy * 64 + iz;
    idx = min(max(idx, 0), G3 - 1);

    // 4 independent divergent requests (1 vox + 3 cp dwords), issued together;
    // tables are L2-resident per XCD thanks to the batch<->XCD pinning.
    float m = 1.0f - voxb[idx];
    const float* cp = cpb + (size_t)idx * 3;
    float dx = rx - cp[0];
    float dy = ry - cp[1];
    float dz = rz - cp[2];
    return (dx * dx + dy * dy + dz * dz) * m;
}

__global__ __launch_bounds__(256, 8) void sym_plane_fused_kernel(
    const float* __restrict__ voxel,     // (B, G,G,G)
    const float* __restrict__ points,    // (B, N, 3)
    const float* __restrict__ closest,   // (B, G^3, 3)
    const float* __restrict__ planes,    // (B, P, 4)
    float* __restrict__ partial,         // (NBLOCKS,) in d_ws
    float* __restrict__ out)             // scalar
{
    // XCD-aware mapping: blocks round-robin over the 8 XCDs, so batch =
    // blockIdx&7 keeps each batch's 4MB of gather tables in ONE XCD's 4MB L2.
    int b = blockIdx.x & 7;
    int i = (blockIdx.x >> 3) * 256 + threadIdx.x;   // 0 .. N-1

    const float* pt = points + ((size_t)b * NN + (size_t)i) * 3;
    // Nontemporal: points are streamed; don't evict the gather tables from L2.
    float px = __builtin_nontemporal_load(pt + 0);
    float py = __builtin_nontemporal_load(pt + 1);
    float pz = __builtin_nontemporal_load(pt + 2);

    // Flat positions f in [12*i, 12*i+12) all map to point i; plane q = f >> 16.
    int f0 = i * 12;
    int q0 = f0 >> 16;
    int q1 = (f0 + 11) >> 16;

    const float* cpb  = closest + (size_t)b * G3 * 3;
    const float* voxb = voxel   + (size_t)b * G3;
    const float4* plb = (const float4*)planes + (size_t)b * PP;

    float sum;
    if (q0 == q1) {
        sum = 12.0f * plane_contrib(px, py, pz, plb[q0], cpb, voxb);
    } else {
        int c0 = (q1 << 16) - f0;     // positions using plane q0
        sum = (float)c0        * plane_contrib(px, py, pz, plb[q0], cpb, voxb)
            + (float)(12 - c0) * plane_contrib(px, py, pz, plb[q1], cpb, voxb);
    }

    // Block reduction: wave64 shuffle, then LDS across 4 waves.
    for (int off = 32; off > 0; off >>= 1)
        sum += __shfl_down(sum, off, 64);

    __shared__ float wsum[4];
    int lane = threadIdx.x & 63;
    int wid  = threadIdx.x >> 6;
    if (lane == 0) wsum[wid] = sum;
    __syncthreads();
    if (threadIdx.x == 0)
        partial[blockIdx.x] = wsum[0] + wsum[1] + wsum[2] + wsum[3];

    // Grid-wide barrier (device-scope release/acquire), then block 0 reduces.
    cg::this_grid().sync();

    if (blockIdx.x == 0) {
        float s = 0.0f;
        #pragma unroll
        for (int j = 0; j < NBLOCKS / 256; ++j)
            s += partial[j * 256 + threadIdx.x];

        for (int off = 32; off > 0; off >>= 1)
            s += __shfl_down(s, off, 64);

        if (lane == 0) wsum[wid] = s;
        __syncthreads();
        if (threadIdx.x == 0)
            out[0] = (wsum[0] + wsum[1] + wsum[2] + wsum[3]) * (1.0f / (float)(BB * PP));
    }
}

extern "C" void kernel_launch(void* const* d_in, const int* in_sizes, int n_in,
                              void* d_out, int out_size, void* d_ws, size_t ws_size,
                              hipStream_t stream) {
    const float* voxel   = (const float*)d_in[0];
    const float* points  = (const float*)d_in[1];
    const float* closest = (const float*)d_in[2];
    const float* planes  = (const float*)d_in[3];
    float* out     = (float*)d_out;
    float* partial = (float*)d_ws;       // NBLOCKS floats, overwritten every call

    void* args[] = { (void*)&voxel, (void*)&points, (void*)&closest,
                     (void*)&planes, (void*)&partial, (void*)&out };
    hipLaunchCooperativeKernel((const void*)sym_plane_fused_kernel,
                               dim3(NBLOCKS), dim3(256), args, 0, stream);
}

// Round 6
// 16.290 us; speedup vs baseline: 10.3100x; 10.3100x over previous
//
#include <hip/hip_runtime.h>

// Problem constants (from reference): B=8, N=65536, P=12, G=64
#define BB 8
#define NN 65536
#define PP 12
#define GG 64
#define G3 (GG*GG*GG)
#define NBLOCKS 2048   // (B*N)/256

// Contribution of reflecting point (px,py,pz) across raw plane pl.
// Matches reference math: normalize plane in f32, reflect, idx3 = ceil((r+0.5)*G-0.5),
// combine in int32 (wraps identically), clip combined index, mask = 1 - voxel.
// Key: when voxel[idx]==1 the reference multiplies the distance by mask=0, so
// the cp gather (3 dwords) and all distance math are dead -> predicate them on
// vox==0. Masked-off lanes issue no memory transactions, cutting divergent L2
// requests by ~30% (voxel occupancy is 0.3).
__device__ __forceinline__ float plane_contrib(
    float px, float py, float pz, float4 pl,
    const float* __restrict__ cpb, const float* __restrict__ voxb)
{
    float nx = pl.x, ny = pl.y, nz = pl.z, d = pl.w;
    float norm = sqrtf(nx * nx + ny * ny + nz * nz);
    float inv = 1.0f / norm;
    nx *= inv; ny *= inv; nz *= inv; d *= inv;

    float t = 2.0f * (px * nx + py * ny + pz * nz + d);
    float rx = px - t * nx;
    float ry = py - t * ny;
    float rz = pz - t * nz;

    int ix = (int)ceilf((rx + 0.5f) * 64.0f - 0.5f);
    int iy = (int)ceilf((ry + 0.5f) * 64.0f - 0.5f);
    int iz = (int)ceilf((rz + 0.5f) * 64.0f - 0.5f);
    int idx = ix * 4096 + iy * 64 + iz;
    idx = min(max(idx, 0), G3 - 1);

    float contrib = 0.0f;
    // voxel values are exactly 0.0f or 1.0f; occupied -> contribution is 0.
    if (voxb[idx] == 0.0f) {
        const float* cp = cpb + (size_t)idx * 3;
        float dx = rx - cp[0];
        float dy = ry - cp[1];
        float dz = rz - cp[2];
        contrib = dx * dx + dy * dy + dz * dz;
    }
    return contrib;
}

__global__ __launch_bounds__(256) void sym_plane_main_kernel(
    const float* __restrict__ voxel,     // (B, G,G,G)
    const float* __restrict__ points,    // (B, N, 3)
    const float* __restrict__ closest,   // (B, G^3, 3)
    const float* __restrict__ planes,    // (B, P, 4)
    float* __restrict__ partial)         // (NBLOCKS,)
{
    // XCD-aware mapping: blocks round-robin over the 8 XCDs, so batch =
    // blockIdx&7 keeps each batch's 4MB of gather tables in ONE XCD's 4MB L2.
    int b = blockIdx.x & 7;
    int i = (blockIdx.x >> 3) * 256 + threadIdx.x;   // 0 .. N-1

    const float* pt = points + ((size_t)b * NN + (size_t)i) * 3;
    // Nontemporal: points are streamed once; don't evict the gather tables.
    float px = __builtin_nontemporal_load(pt + 0);
    float py = __builtin_nontemporal_load(pt + 1);
    float pz = __builtin_nontemporal_load(pt + 2);

    // Flat positions f in [12*i, 12*i+12) all map to point i; plane q = f >> 16.
    int f0 = i * 12;
    int q0 = f0 >> 16;
    int q1 = (f0 + 11) >> 16;

    const float* cpb  = closest + (size_t)b * G3 * 3;
    const float* voxb = voxel   + (size_t)b * G3;
    const float4* plb = (const float4*)planes + (size_t)b * PP;

    float sum;
    if (q0 == q1) {
        sum = 12.0f * plane_contrib(px, py, pz, plb[q0], cpb, voxb);
    } else {
        int c0 = (q1 << 16) - f0;     // positions using plane q0 (11 threads/batch)
        sum = (float)c0        * plane_contrib(px, py, pz, plb[q0], cpb, voxb)
            + (float)(12 - c0) * plane_contrib(px, py, pz, plb[q1], cpb, voxb);
    }

    // Block reduction: wave64 shuffle, then LDS across 4 waves.
    for (int off = 32; off > 0; off >>= 1)
        sum += __shfl_down(sum, off, 64);

    __shared__ float wsum[4];
    int lane = threadIdx.x & 63;
    int wid  = threadIdx.x >> 6;
    if (lane == 0) wsum[wid] = sum;
    __syncthreads();
    if (threadIdx.x == 0)
        __builtin_nontemporal_store(wsum[0] + wsum[1] + wsum[2] + wsum[3],
                                    partial + blockIdx.x);
}

// Single-block final reduce: overwrites out[0] (no pre-zero needed, fixed
// summation order, no atomics -> deterministic).
__global__ __launch_bounds__(256) void sym_plane_reduce_kernel(
    const float* __restrict__ partial, float* __restrict__ out)
{
    float s = 0.0f;
    for (int j = threadIdx.x; j < NBLOCKS; j += 256)
        s += partial[j];

    for (int off = 32; off > 0; off >>= 1)
        s += __shfl_down(s, off, 64);

    __shared__ float wsum[4];
    int lane = threadIdx.x & 63;
    int wid  = threadIdx.x >> 6;
    if (lane == 0) wsum[wid] = s;
    __syncthreads();
    if (threadIdx.x == 0)
        out[0] = (wsum[0] + wsum[1] + wsum[2] + wsum[3]) * (1.0f / (float)(BB * PP));
}

extern "C" void kernel_launch(void* const* d_in, const int* in_sizes, int n_in,
                              void* d_out, int out_size, void* d_ws, size_t ws_size,
                              hipStream_t stream) {
    const float* voxel   = (const float*)d_in[0];
    const float* points  = (const float*)d_in[1];
    const float* closest = (const float*)d_in[2];
    const float* planes  = (const float*)d_in[3];
    float* out     = (float*)d_out;
    float* partial = (float*)d_ws;       // NBLOCKS floats, overwritten every call

    hipLaunchKernelGGL(sym_plane_main_kernel, dim3(NBLOCKS), dim3(256), 0, stream,
                       voxel, points, closest, planes, partial);
    hipLaunchKernelGGL(sym_plane_reduce_kernel, dim3(1), dim3(256), 0, stream,
                       partial, out);
}